// Round 6
// baseline (112.172 us; speedup 1.0000x reference)
//
#include <hip/hip_runtime.h>
#include <hip/hip_bf16.h>
#include <stdint.h>

#define S_LEN 4096
#define DIM   512
#define NH    8
#define HD    64
// 0.125 * log2(e): fold softmax base-2 conversion into the Q projection weights
#define QSCALE 0.18033688011112042f

typedef __attribute__((ext_vector_type(8))) short short8;
typedef __attribute__((ext_vector_type(4))) float f32x4;
typedef __attribute__((ext_vector_type(16))) float f32x16;
typedef __attribute__((ext_vector_type(2))) unsigned uint2v;

__device__ __forceinline__ uint32_t pk2(float lo, float hi) {
  union { __hip_bfloat162 h; uint32_t u; } cv;
  cv.h = __float22bfloat162_rn(float2{lo, hi});
  return cv.u;
}
__device__ __forceinline__ ushort bf1(float x) {
  union { __hip_bfloat16 b; ushort u; } cv;
  cv.b = __float2bfloat16(x);
  return cv.u;
}
__device__ __forceinline__ float bf2f(ushort u) {
  union { uint32_t u; float f; } cv;
  cv.u = (uint32_t)u << 16;
  return cv.f;
}

// ---------------- prep: x -> bf16 ----------------
__global__ __launch_bounds__(256)
void cast_x(const float* __restrict__ src, ushort* __restrict__ dst) {
  const int i = (blockIdx.x * 256 + threadIdx.x) * 8;
  const float4 a = *reinterpret_cast<const float4*>(src + i);
  const float4 b = *reinterpret_cast<const float4*>(src + i + 4);
  uint4 o;
  o.x = pk2(a.x, a.y); o.y = pk2(a.z, a.w);
  o.z = pk2(b.x, b.y); o.w = pk2(b.z, b.w);
  *reinterpret_cast<uint4*>(dst + i) = o;
}

// ---------------- prep: transpose weights to bf16 ----------------
__global__ __launch_bounds__(256)
void transpose_w(const float* __restrict__ qp, const float* __restrict__ kp,
                 const float* __restrict__ vp, const float* __restrict__ pp,
                 ushort* __restrict__ wbT, ushort* __restrict__ ppT) {
  __shared__ float L[64][65];
  const int z = blockIdx.z;
  const float* src = (z == 0) ? qp : (z == 1) ? kp : (z == 2) ? vp : pp;
  ushort* dst = (z < 3) ? (wbT + (size_t)z * 512 * 512) : ppT;
  const float scale = (z == 0) ? QSCALE : 1.0f;
  const int k0 = blockIdx.x * 64, n0 = blockIdx.y * 64;
  const int r = threadIdx.x >> 2, c0 = (threadIdx.x & 3) * 16;

#pragma unroll
  for (int j = 0; j < 4; ++j) {
    const float4 v =
        *reinterpret_cast<const float4*>(&src[(k0 + r) * 512 + n0 + c0 + 4 * j]);
    L[r][c0 + 4 * j + 0] = v.x * scale;
    L[r][c0 + 4 * j + 1] = v.y * scale;
    L[r][c0 + 4 * j + 2] = v.z * scale;
    L[r][c0 + 4 * j + 3] = v.w * scale;
  }
  __syncthreads();

  uint4 u0, u1;
  u0.x = pk2(L[c0 + 0][r], L[c0 + 1][r]);
  u0.y = pk2(L[c0 + 2][r], L[c0 + 3][r]);
  u0.z = pk2(L[c0 + 4][r], L[c0 + 5][r]);
  u0.w = pk2(L[c0 + 6][r], L[c0 + 7][r]);
  u1.x = pk2(L[c0 + 8][r], L[c0 + 9][r]);
  u1.y = pk2(L[c0 + 10][r], L[c0 + 11][r]);
  u1.z = pk2(L[c0 + 12][r], L[c0 + 13][r]);
  u1.w = pk2(L[c0 + 14][r], L[c0 + 15][r]);
  ushort* d = dst + (size_t)(n0 + r) * 512 + k0 + c0;
  *reinterpret_cast<uint4*>(d) = u0;
  *reinterpret_cast<uint4*>(d + 8) = u1;
}

// ---------------- bf16 MFMA GEMM ----------------
// MODE 0: qkv out. Q,K planes row-major [4096][64]; V plane TRANSPOSED [64][4096].
// MODE 1: f32 [M][512] out.
template <int MODE>
__global__ __launch_bounds__(256)
void gemm_bf16(const ushort* __restrict__ A, const ushort* __restrict__ Bt,
               void* __restrict__ Cout) {
  __shared__ __align__(16) unsigned char lds[24576];
  const int tid = threadIdx.x;
  const int m0 = blockIdx.x * 128, n0 = blockIdx.y * 64;
  const int lane = tid & 63, w = tid >> 6;
  const int wm = w >> 1, wn = w & 1;
  const int q = lane & 15, g = lane >> 4;
  f32x4 acc[4][2] = {};

  const int ar = tid >> 1, ah = tid & 1;
  const int br = tid >> 2, bq = tid & 3;

  for (int k0 = 0; k0 < 512; k0 += 64) {
    const ushort* ag = A + (size_t)(m0 + ar) * 512 + k0 + ah * 32;
    const uint4 a0 = *reinterpret_cast<const uint4*>(ag);
    const uint4 a1 = *reinterpret_cast<const uint4*>(ag + 8);
    const uint4 a2 = *reinterpret_cast<const uint4*>(ag + 16);
    const uint4 a3 = *reinterpret_cast<const uint4*>(ag + 24);
    const ushort* bg = Bt + (size_t)(n0 + br) * 512 + k0 + bq * 16;
    const uint4 b0 = *reinterpret_cast<const uint4*>(bg);
    const uint4 b1 = *reinterpret_cast<const uint4*>(bg + 8);
    __syncthreads();
    {
      unsigned char* ab = lds + ar * 128;
      const int asw = (ar & 7) << 4;
      *reinterpret_cast<uint4*>(ab + ((ah * 64 + 0) ^ asw)) = a0;
      *reinterpret_cast<uint4*>(ab + ((ah * 64 + 16) ^ asw)) = a1;
      *reinterpret_cast<uint4*>(ab + ((ah * 64 + 32) ^ asw)) = a2;
      *reinterpret_cast<uint4*>(ab + ((ah * 64 + 48) ^ asw)) = a3;
      unsigned char* bb = lds + 16384 + br * 128;
      const int bsw = (br & 7) << 4;
      *reinterpret_cast<uint4*>(bb + ((bq * 32 + 0) ^ bsw)) = b0;
      *reinterpret_cast<uint4*>(bb + ((bq * 32 + 16) ^ bsw)) = b1;
    }
    __syncthreads();

#pragma unroll
    for (int ks = 0; ks < 2; ++ks) {
      short8 bf[2];
#pragma unroll
      for (int ni = 0; ni < 2; ++ni) {
        const int rn = wn * 32 + ni * 16 + q;
        bf[ni] = *reinterpret_cast<const short8*>(
            lds + 16384 + rn * 128 + ((64 * ks + 16 * g) ^ ((rn & 7) << 4)));
      }
#pragma unroll
      for (int mi = 0; mi < 4; ++mi) {
        const int rm = wm * 64 + mi * 16 + q;
        const short8 af = *reinterpret_cast<const short8*>(
            lds + rm * 128 + ((64 * ks + 16 * g) ^ ((rm & 7) << 4)));
#pragma unroll
        for (int ni = 0; ni < 2; ++ni)
          acc[mi][ni] = __builtin_amdgcn_mfma_f32_16x16x32_bf16(
              af, bf[ni], acc[mi][ni], 0, 0, 0);
      }
    }
  }

  if (MODE == 0) {
    ushort* C = (ushort*)Cout;
    const int which = n0 >> 9;  // block-uniform
#pragma unroll
    for (int ni = 0; ni < 2; ++ni) {
      const int n = n0 + wn * 32 + ni * 16 + q;
      const int rem = n & 511, hh = rem >> 6, d = rem & 63;
      if (which == 2) {  // V transposed: [64 d][4096 s]
        ushort* base = C + (size_t)(2 * NH + hh) * (size_t)(S_LEN * HD) +
                       (size_t)d * S_LEN;
#pragma unroll
        for (int mi = 0; mi < 4; ++mi) {
          const int s = m0 + wm * 64 + mi * 16 + 4 * g;
          uint2 pw;
          pw.x = pk2(acc[mi][ni][0], acc[mi][ni][1]);
          pw.y = pk2(acc[mi][ni][2], acc[mi][ni][3]);
          *reinterpret_cast<uint2*>(base + s) = pw;
        }
      } else {
        ushort* base =
            C + ((size_t)which * NH + hh) * (size_t)(S_LEN * HD) + d;
#pragma unroll
        for (int mi = 0; mi < 4; ++mi) {
          const int s = m0 + wm * 64 + mi * 16 + 4 * g;
#pragma unroll
          for (int r = 0; r < 4; ++r)
            base[(size_t)(s + r) * HD] = bf1(acc[mi][ni][r]);
        }
      }
    }
  } else {
    float* C = (float*)Cout;
#pragma unroll
    for (int ni = 0; ni < 2; ++ni) {
      const int n = n0 + wn * 32 + ni * 16 + q;
#pragma unroll
      for (int mi = 0; mi < 4; ++mi) {
        const int s = m0 + wm * 64 + mi * 16 + 4 * g;
#pragma unroll
        for (int r = 0; r < 4; ++r)
          C[(size_t)(s + r) * 512 + n] = acc[mi][ni][r];
      }
    }
  }
}

// ---------------- MFMA flash attention, 32x32, KV-split-4 ----------------
// Block: 256 thr = 4 waves; wave w owns q rows qb*128 + w*32 .. +31.
// blockIdx.x = combo = z*8 + h (kv chunk z of head h); blockIdx.y = qb.
// S^T = K*Q^T (lane&31 = q col); O^T = V^T * P^T (lane&31 = q col too) so all
// softmax state is lane-local. P redistributed in-register via cvt_pk +
// permlane32_swap. Partials (unnormalized O^T, m, l) written to global;
// combine kernel merges the 4 chunks.
__global__ __launch_bounds__(256)
void attn_mfma32(const ushort* __restrict__ QKV, ushort* __restrict__ Opart,
                 float2* __restrict__ ML) {
  __shared__ __align__(16) unsigned char lds[16384];  // K 8K | Vt 8K
  const int tid = threadIdx.x;
  const int combo = blockIdx.x;
  const int h = combo & 7, z = combo >> 3;
  const int qb = blockIdx.y;
  const int lane = tid & 63, w = tid >> 6;
  const int r31 = lane & 31, hh = lane >> 5;

  const size_t plane = (size_t)S_LEN * HD;
  const ushort* Qp = QKV + (size_t)h * plane;
  const ushort* Kp = QKV + (size_t)(NH + h) * plane;       // [4096][64]
  const ushort* Vp = QKV + (size_t)(2 * NH + h) * plane;   // [64][4096]

  const int qrow = qb * 128 + w * 32 + r31;

  // Q fragments: qf[ks] = Q[qrow][16ks + 8hh .. +7]
  short8 qf[4];
  {
    const ushort* qptr = Qp + (size_t)qrow * HD + 8 * hh;
#pragma unroll
    for (int ks = 0; ks < 4; ++ks)
      qf[ks] = *reinterpret_cast<const short8*>(qptr + 16 * ks);
  }

  // per-(ks) swizzled fragment-read addresses (K at 0 / Vt at 8192, +4096/subtile)
  int raddr[4];
#pragma unroll
  for (int ks = 0; ks < 4; ++ks)
    raddr[ks] = r31 * 128 + (((2 * ks + hh) ^ (r31 & 7)) << 4);

  // staging: thread -> (row 0..63, 32B segment 0..3)
  const int trow = tid >> 2, seg = tid & 3;
  const int swr = (trow & 7) << 4;
  const int wk0 = trow * 128 + ((seg * 32) ^ swr);
  const int wk1 = trow * 128 + ((seg * 32 + 16) ^ swr);
  const ushort* kgbase = Kp + (size_t)(z * 1024 + trow) * HD + seg * 16;
  const ushort* vgbase = Vp + (size_t)trow * S_LEN + z * 1024 + seg * 16;

  f32x16 o[2] = {};
  float m_i = -1e30f, l_i = 0.f;

  uint4 kA = *reinterpret_cast<const uint4*>(kgbase);
  uint4 kB = *reinterpret_cast<const uint4*>(kgbase + 8);
  uint4 vA = *reinterpret_cast<const uint4*>(vgbase);
  uint4 vB = *reinterpret_cast<const uint4*>(vgbase + 8);

  for (int t = 0; t < 16; ++t) {
    __syncthreads();  // previous tile's fragment reads complete
    *reinterpret_cast<uint4*>(lds + wk0) = kA;
    *reinterpret_cast<uint4*>(lds + wk1) = kB;
    *reinterpret_cast<uint4*>(lds + 8192 + wk0) = vA;
    *reinterpret_cast<uint4*>(lds + 8192 + wk1) = vB;
    __syncthreads();

    // prefetch next tile (wraps on last iter; data unused)
    const int tn = (t + 1) & 15;
    kA = *reinterpret_cast<const uint4*>(kgbase + tn * 4096);
    kB = *reinterpret_cast<const uint4*>(kgbase + tn * 4096 + 8);
    vA = *reinterpret_cast<const uint4*>(vgbase + tn * 64);
    vB = *reinterpret_cast<const uint4*>(vgbase + tn * 64 + 8);

    // ---- S^T = K * Q^T  (two 32-row kpos subtiles) ----
    f32x16 s0 = {}, s1 = {};
#pragma unroll
    for (int ks = 0; ks < 4; ++ks) {
      const short8 a0 = *reinterpret_cast<const short8*>(lds + raddr[ks]);
      const short8 a1 = *reinterpret_cast<const short8*>(lds + raddr[ks] + 4096);
      s0 = __builtin_amdgcn_mfma_f32_32x32x16_bf16(a0, qf[ks], s0, 0, 0, 0);
      s1 = __builtin_amdgcn_mfma_f32_32x32x16_bf16(a1, qf[ks], s1, 0, 0, 0);
    }

    // ---- online softmax (base 2), deferred-max THR=8 ----
    float mv[8];
#pragma unroll
    for (int i = 0; i < 8; ++i)
      mv[i] = fmaxf(fmaxf(s0[i], s0[i + 8]), fmaxf(s1[i], s1[i + 8]));
#pragma unroll
    for (int i = 0; i < 4; ++i) mv[i] = fmaxf(mv[i], mv[i + 4]);
    float mx = fmaxf(fmaxf(mv[0], mv[1]), fmaxf(mv[2], mv[3]));
    mx = fmaxf(mx, __shfl_xor(mx, 32));

    const bool grow = mx > m_i + 8.0f;
    if (__any(grow)) {
      const float mn = grow ? mx : m_i;
      const float alpha = grow ? exp2f(m_i - mn) : 1.0f;
      l_i *= alpha;
#pragma unroll
      for (int i = 0; i < 16; ++i) { o[0][i] *= alpha; o[1][i] *= alpha; }
      m_i = mn;
    }

    float r0 = 0.f, r1 = 0.f, r2 = 0.f, r3 = 0.f;
#pragma unroll
    for (int i = 0; i < 16; i += 4) {
      s0[i + 0] = exp2f(s0[i + 0] - m_i); r0 += s0[i + 0];
      s0[i + 1] = exp2f(s0[i + 1] - m_i); r1 += s0[i + 1];
      s0[i + 2] = exp2f(s0[i + 2] - m_i); r2 += s0[i + 2];
      s0[i + 3] = exp2f(s0[i + 3] - m_i); r3 += s0[i + 3];
      s1[i + 0] = exp2f(s1[i + 0] - m_i); r0 += s1[i + 0];
      s1[i + 1] = exp2f(s1[i + 1] - m_i); r1 += s1[i + 1];
      s1[i + 2] = exp2f(s1[i + 2] - m_i); r2 += s1[i + 2];
      s1[i + 3] = exp2f(s1[i + 3] - m_i); r3 += s1[i + 3];
    }
    float rs = (r0 + r1) + (r2 + r3);
    rs += __shfl_xor(rs, 32);
    l_i += rs;

    // ---- P -> bf16 kpairs, redistribute across lane halves ----
    // u[mt][b][e] holds kpair 4b + 2hh + e of subtile mt.
    uint32_t u[2][4][2];
#pragma unroll
    for (int b = 0; b < 4; ++b)
#pragma unroll
      for (int e = 0; e < 2; ++e) {
        u[0][b][e] = pk2(s0[4 * b + 2 * e], s0[4 * b + 2 * e + 1]);
        u[1][b][e] = pk2(s1[4 * b + 2 * e], s1[4 * b + 2 * e + 1]);
      }
    short8 pf[4];
#pragma unroll
    for (int ks = 0; ks < 4; ++ks) {
      const int mt = ks >> 1, bb = 2 * (ks & 1);
      const uint2v se0 =
          __builtin_amdgcn_permlane32_swap(u[mt][bb][0], u[mt][bb + 1][0],
                                           false, false);
      const uint2v se1 =
          __builtin_amdgcn_permlane32_swap(u[mt][bb][1], u[mt][bb + 1][1],
                                           false, false);
      uint32_t fr[4] = {se0.x, se1.x, se0.y, se1.y};
      pf[ks] = *reinterpret_cast<short8*>(fr);
    }

    // ---- O^T += V^T * P^T ----
#pragma unroll
    for (int dt = 0; dt < 2; ++dt)
#pragma unroll
      for (int ks = 0; ks < 4; ++ks) {
        const short8 vf = *reinterpret_cast<const short8*>(
            lds + 8192 + dt * 4096 + raddr[ks]);
        o[dt] = __builtin_amdgcn_mfma_f32_32x32x16_bf16(vf, pf[ks], o[dt],
                                                        0, 0, 0);
      }
  }

  // ---- store partials ----
  if (lane < 32) ML[(size_t)combo * S_LEN + qrow] = float2{m_i, l_i};
  ushort* ob = Opart + (size_t)combo * 64 * S_LEN + qrow;
#pragma unroll
  for (int dt = 0; dt < 2; ++dt)
#pragma unroll
    for (int r = 0; r < 16; ++r) {
      const int d = 32 * dt + (r & 3) + 8 * (r >> 2) + 4 * hh;
      ob[(size_t)d * S_LEN] = bf1(o[dt][r]);
    }
}

// ---------------- combine the 4 kv-chunk partials ----------------
__global__ __launch_bounds__(256)
void combine(const ushort* __restrict__ Opart, const float2* __restrict__ ML,
             ushort* __restrict__ ob) {
  const int t = threadIdx.x;
  const int qq = t & 63, ds = t >> 6;
  const int q = blockIdx.x * 64 + qq;
  const int h = blockIdx.y;

  float m = -1e30f, mz[4], lz[4];
#pragma unroll
  for (int z = 0; z < 4; ++z) {
    const float2 v = ML[(size_t)(z * 8 + h) * S_LEN + q];
    mz[z] = v.x; lz[z] = v.y;
    m = fmaxf(m, v.x);
  }
  float wz[4], l = 0.f;
#pragma unroll
  for (int z = 0; z < 4; ++z) {
    wz[z] = exp2f(mz[z] - m);
    l += wz[z] * lz[z];
  }
  const float inv = 1.0f / l;

  float acc[16];
#pragma unroll
  for (int i = 0; i < 16; ++i) acc[i] = 0.f;
#pragma unroll
  for (int z = 0; z < 4; ++z) {
    const ushort* src =
        Opart + ((size_t)(z * 8 + h) * 64 + ds * 16) * S_LEN + q;
#pragma unroll
    for (int i = 0; i < 16; ++i)
      acc[i] += wz[z] * bf2f(src[(size_t)i * S_LEN]);
  }
  uint32_t pk[8];
#pragma unroll
  for (int i = 0; i < 8; ++i)
    pk[i] = pk2(acc[2 * i] * inv, acc[2 * i + 1] * inv);
  ushort* dst = ob + (size_t)q * DIM + h * 64 + ds * 16;
  *reinterpret_cast<uint4*>(dst) = *reinterpret_cast<uint4*>(pk);
  *reinterpret_cast<uint4*>(dst + 8) = *reinterpret_cast<uint4*>(pk + 4);
}

extern "C" void kernel_launch(void* const* d_in, const int* in_sizes, int n_in,
                              void* d_out, int out_size, void* d_ws, size_t ws_size,
                              hipStream_t stream) {
  const float* x  = (const float*)d_in[0];
  const float* qp = (const float*)d_in[1];
  const float* kp = (const float*)d_in[2];
  const float* vp = (const float*)d_in[3];
  const float* pp = (const float*)d_in[4];
  float* out = (float*)d_out;

  unsigned char* ws = (unsigned char*)d_ws;
  ushort* xb    = (ushort*)(ws);                       // 4 MB
  ushort* qkvb  = (ushort*)(ws + ((size_t)4 << 20));   // 12 MB [3][8] planes
  ushort* ob    = (ushort*)(ws + ((size_t)16 << 20));  // 4 MB [4096][512]
  ushort* wbT   = (ushort*)(ws + ((size_t)20 << 20));  // 1.5 MB
  ushort* ppT   = (ushort*)(ws + ((size_t)22 << 20));  // 0.5 MB
  ushort* opart = (ushort*)(ws + ((size_t)23 << 20));  // 16 MB [32][64][4096]
  float2* ml    = (float2*)(ws + ((size_t)39 << 20));  // 1 MB [32][4096]

  cast_x<<<dim3(1024), dim3(256), 0, stream>>>(x, xb);
  transpose_w<<<dim3(8, 8, 4), dim3(256), 0, stream>>>(qp, kp, vp, pp, wbT, ppT);
  gemm_bf16<0><<<dim3(32, 24), dim3(256), 0, stream>>>(xb, wbT, qkvb);
  attn_mfma32<<<dim3(32, 32), dim3(256), 0, stream>>>(qkvb, opart, ml);
  combine<<<dim3(64, 8), dim3(256), 0, stream>>>(opart, ml, ob);
  gemm_bf16<1><<<dim3(32, 8), dim3(256), 0, stream>>>(ob, ppT, out);
}

// Round 7
// 96.707 us; speedup vs baseline: 1.1599x; 1.1599x over previous
//
#include <hip/hip_runtime.h>
#include <hip/hip_bf16.h>
#include <stdint.h>

#define S_LEN 4096
#define DIM   512
#define NH    8
#define HD    64
// 0.125 * log2(e): fold softmax base-2 conversion into the Q projection weights
#define QSCALE 0.18033688011112042f

typedef __attribute__((ext_vector_type(8))) short short8;
typedef __attribute__((ext_vector_type(4))) float f32x4;
typedef __attribute__((ext_vector_type(16))) float f32x16;
typedef __attribute__((ext_vector_type(2))) unsigned uint2v;

__device__ __forceinline__ uint32_t pk2(float lo, float hi) {
  union { __hip_bfloat162 h; uint32_t u; } cv;
  cv.h = __float22bfloat162_rn(float2{lo, hi});
  return cv.u;
}
__device__ __forceinline__ ushort bf1(float x) {
  union { __hip_bfloat16 b; ushort u; } cv;
  cv.b = __float2bfloat16(x);
  return cv.u;
}
__device__ __forceinline__ float bf2f(ushort u) {
  union { uint32_t u; float f; } cv;
  cv.u = (uint32_t)u << 16;
  return cv.f;
}
// raw v_exp_f32: 2^x, single instruction (args bounded by defer-max, no fixup)
__device__ __forceinline__ float fexp2(float x) {
  float r;
  asm("v_exp_f32 %0, %1" : "=v"(r) : "v"(x));
  return r;
}

// ---------------- prep: x -> bf16 ----------------
__global__ __launch_bounds__(256)
void cast_x(const float* __restrict__ src, ushort* __restrict__ dst) {
  const int i = (blockIdx.x * 256 + threadIdx.x) * 8;
  const float4 a = *reinterpret_cast<const float4*>(src + i);
  const float4 b = *reinterpret_cast<const float4*>(src + i + 4);
  uint4 o;
  o.x = pk2(a.x, a.y); o.y = pk2(a.z, a.w);
  o.z = pk2(b.x, b.y); o.w = pk2(b.z, b.w);
  *reinterpret_cast<uint4*>(dst + i) = o;
}

// ---------------- prep: transpose weights to bf16 ----------------
__global__ __launch_bounds__(256)
void transpose_w(const float* __restrict__ qp, const float* __restrict__ kp,
                 const float* __restrict__ vp, const float* __restrict__ pp,
                 ushort* __restrict__ wbT, ushort* __restrict__ ppT) {
  __shared__ float L[64][65];
  const int z = blockIdx.z;
  const float* src = (z == 0) ? qp : (z == 1) ? kp : (z == 2) ? vp : pp;
  ushort* dst = (z < 3) ? (wbT + (size_t)z * 512 * 512) : ppT;
  const float scale = (z == 0) ? QSCALE : 1.0f;
  const int k0 = blockIdx.x * 64, n0 = blockIdx.y * 64;
  const int r = threadIdx.x >> 2, c0 = (threadIdx.x & 3) * 16;

#pragma unroll
  for (int j = 0; j < 4; ++j) {
    const float4 v =
        *reinterpret_cast<const float4*>(&src[(k0 + r) * 512 + n0 + c0 + 4 * j]);
    L[r][c0 + 4 * j + 0] = v.x * scale;
    L[r][c0 + 4 * j + 1] = v.y * scale;
    L[r][c0 + 4 * j + 2] = v.z * scale;
    L[r][c0 + 4 * j + 3] = v.w * scale;
  }
  __syncthreads();

  uint4 u0, u1;
  u0.x = pk2(L[c0 + 0][r], L[c0 + 1][r]);
  u0.y = pk2(L[c0 + 2][r], L[c0 + 3][r]);
  u0.z = pk2(L[c0 + 4][r], L[c0 + 5][r]);
  u0.w = pk2(L[c0 + 6][r], L[c0 + 7][r]);
  u1.x = pk2(L[c0 + 8][r], L[c0 + 9][r]);
  u1.y = pk2(L[c0 + 10][r], L[c0 + 11][r]);
  u1.z = pk2(L[c0 + 12][r], L[c0 + 13][r]);
  u1.w = pk2(L[c0 + 14][r], L[c0 + 15][r]);
  ushort* d = dst + (size_t)(n0 + r) * 512 + k0 + c0;
  *reinterpret_cast<uint4*>(d) = u0;
  *reinterpret_cast<uint4*>(d + 8) = u1;
}

// ---------------- bf16 MFMA GEMM ----------------
// MODE 0: qkv out. Q,K planes row-major [4096][64]; V plane TRANSPOSED [64][4096].
// MODE 1: f32 [M][512] out.
template <int MODE>
__global__ __launch_bounds__(256)
void gemm_bf16(const ushort* __restrict__ A, const ushort* __restrict__ Bt,
               void* __restrict__ Cout) {
  __shared__ __align__(16) unsigned char lds[24576];
  const int tid = threadIdx.x;
  const int m0 = blockIdx.x * 128, n0 = blockIdx.y * 64;
  const int lane = tid & 63, w = tid >> 6;
  const int wm = w >> 1, wn = w & 1;
  const int q = lane & 15, g = lane >> 4;
  f32x4 acc[4][2] = {};

  const int ar = tid >> 1, ah = tid & 1;
  const int br = tid >> 2, bq = tid & 3;

  for (int k0 = 0; k0 < 512; k0 += 64) {
    const ushort* ag = A + (size_t)(m0 + ar) * 512 + k0 + ah * 32;
    const uint4 a0 = *reinterpret_cast<const uint4*>(ag);
    const uint4 a1 = *reinterpret_cast<const uint4*>(ag + 8);
    const uint4 a2 = *reinterpret_cast<const uint4*>(ag + 16);
    const uint4 a3 = *reinterpret_cast<const uint4*>(ag + 24);
    const ushort* bg = Bt + (size_t)(n0 + br) * 512 + k0 + bq * 16;
    const uint4 b0 = *reinterpret_cast<const uint4*>(bg);
    const uint4 b1 = *reinterpret_cast<const uint4*>(bg + 8);
    __syncthreads();
    {
      unsigned char* ab = lds + ar * 128;
      const int asw = (ar & 7) << 4;
      *reinterpret_cast<uint4*>(ab + ((ah * 64 + 0) ^ asw)) = a0;
      *reinterpret_cast<uint4*>(ab + ((ah * 64 + 16) ^ asw)) = a1;
      *reinterpret_cast<uint4*>(ab + ((ah * 64 + 32) ^ asw)) = a2;
      *reinterpret_cast<uint4*>(ab + ((ah * 64 + 48) ^ asw)) = a3;
      unsigned char* bb = lds + 16384 + br * 128;
      const int bsw = (br & 7) << 4;
      *reinterpret_cast<uint4*>(bb + ((bq * 32 + 0) ^ bsw)) = b0;
      *reinterpret_cast<uint4*>(bb + ((bq * 32 + 16) ^ bsw)) = b1;
    }
    __syncthreads();

#pragma unroll
    for (int ks = 0; ks < 2; ++ks) {
      short8 bf[2];
#pragma unroll
      for (int ni = 0; ni < 2; ++ni) {
        const int rn = wn * 32 + ni * 16 + q;
        bf[ni] = *reinterpret_cast<const short8*>(
            lds + 16384 + rn * 128 + ((64 * ks + 16 * g) ^ ((rn & 7) << 4)));
      }
#pragma unroll
      for (int mi = 0; mi < 4; ++mi) {
        const int rm = wm * 64 + mi * 16 + q;
        const short8 af = *reinterpret_cast<const short8*>(
            lds + rm * 128 + ((64 * ks + 16 * g) ^ ((rm & 7) << 4)));
#pragma unroll
        for (int ni = 0; ni < 2; ++ni)
          acc[mi][ni] = __builtin_amdgcn_mfma_f32_16x16x32_bf16(
              af, bf[ni], acc[mi][ni], 0, 0, 0);
      }
    }
  }

  if (MODE == 0) {
    ushort* C = (ushort*)Cout;
    const int which = n0 >> 9;  // block-uniform
#pragma unroll
    for (int ni = 0; ni < 2; ++ni) {
      const int n = n0 + wn * 32 + ni * 16 + q;
      const int rem = n & 511, hh = rem >> 6, d = rem & 63;
      if (which == 2) {  // V transposed: [64 d][4096 s]
        ushort* base = C + (size_t)(2 * NH + hh) * (size_t)(S_LEN * HD) +
                       (size_t)d * S_LEN;
#pragma unroll
        for (int mi = 0; mi < 4; ++mi) {
          const int s = m0 + wm * 64 + mi * 16 + 4 * g;
          uint2 pw;
          pw.x = pk2(acc[mi][ni][0], acc[mi][ni][1]);
          pw.y = pk2(acc[mi][ni][2], acc[mi][ni][3]);
          *reinterpret_cast<uint2*>(base + s) = pw;
        }
      } else {
        ushort* base =
            C + ((size_t)which * NH + hh) * (size_t)(S_LEN * HD) + d;
#pragma unroll
        for (int mi = 0; mi < 4; ++mi) {
          const int s = m0 + wm * 64 + mi * 16 + 4 * g;
#pragma unroll
          for (int r = 0; r < 4; ++r)
            base[(size_t)(s + r) * HD] = bf1(acc[mi][ni][r]);
        }
      }
    }
  } else {
    float* C = (float*)Cout;
#pragma unroll
    for (int ni = 0; ni < 2; ++ni) {
      const int n = n0 + wn * 32 + ni * 16 + q;
#pragma unroll
      for (int mi = 0; mi < 4; ++mi) {
        const int s = m0 + wm * 64 + mi * 16 + 4 * g;
#pragma unroll
        for (int r = 0; r < 4; ++r)
          C[(size_t)(s + r) * 512 + n] = acc[mi][ni][r];
      }
    }
  }
}

// ---------------- MFMA flash attention, 32x32, KV-split-4 ----------------
// Block: 256 thr = 4 waves; wave w owns q rows qb*128 + w*32 .. +31.
// blockIdx.x = combo = z*8 + h; blockIdx.y = qb.
// Double-buffered LDS (2 x 16KB: K 8K | Vt 8K per buffer), ONE barrier/tile:
//   ds_write buf[p] -> barrier -> issue next loads -> compute buf[p].
__global__ __launch_bounds__(256, 4)
void attn_mfma32(const ushort* __restrict__ QKV, ushort* __restrict__ Opart,
                 float2* __restrict__ ML) {
  __shared__ __align__(16) unsigned char lds[32768];
  const int tid = threadIdx.x;
  const int combo = blockIdx.x;
  const int h = combo & 7, z = combo >> 3;
  const int qb = blockIdx.y;
  const int lane = tid & 63, w = tid >> 6;
  const int r31 = lane & 31, hh = lane >> 5;

  const size_t plane = (size_t)S_LEN * HD;
  const ushort* Qp = QKV + (size_t)h * plane;
  const ushort* Kp = QKV + (size_t)(NH + h) * plane;       // [4096][64]
  const ushort* Vp = QKV + (size_t)(2 * NH + h) * plane;   // [64][4096]

  const int qrow = qb * 128 + w * 32 + r31;

  // Q fragments: qf[ks] = Q[qrow][16ks + 8hh .. +7]
  short8 qf[4];
  {
    const ushort* qptr = Qp + (size_t)qrow * HD + 8 * hh;
#pragma unroll
    for (int ks = 0; ks < 4; ++ks)
      qf[ks] = *reinterpret_cast<const short8*>(qptr + 16 * ks);
  }

  // per-(ks) swizzled fragment-read addresses within a buffer
  int raddr[4];
#pragma unroll
  for (int ks = 0; ks < 4; ++ks)
    raddr[ks] = r31 * 128 + (((2 * ks + hh) ^ (r31 & 7)) << 4);

  // staging: thread -> (row 0..63, 32B segment 0..3)
  const int trow = tid >> 2, seg = tid & 3;
  const int swr = (trow & 7) << 4;
  const int wk0 = trow * 128 + ((seg * 32) ^ swr);
  const int wk1 = trow * 128 + ((seg * 32 + 16) ^ swr);
  const ushort* kgbase = Kp + (size_t)(z * 1024 + trow) * HD + seg * 16;
  const ushort* vgbase = Vp + (size_t)trow * S_LEN + z * 1024 + seg * 16;

  f32x16 o[2] = {};
  float m_i = -1e30f, l_i = 0.f;

  uint4 kA = *reinterpret_cast<const uint4*>(kgbase);
  uint4 kB = *reinterpret_cast<const uint4*>(kgbase + 8);
  uint4 vA = *reinterpret_cast<const uint4*>(vgbase);
  uint4 vB = *reinterpret_cast<const uint4*>(vgbase + 8);

  for (int t = 0; t < 16; ++t) {
    const int po = (t & 1) << 14;  // buffer select (0 / 16384)
    *reinterpret_cast<uint4*>(lds + (wk0 | po)) = kA;
    *reinterpret_cast<uint4*>(lds + (wk1 | po)) = kB;
    *reinterpret_cast<uint4*>(lds + ((8192 + wk0) | po)) = vA;
    *reinterpret_cast<uint4*>(lds + ((8192 + wk1) | po)) = vB;
    __syncthreads();

    // issue next tile's loads (wraps on last iter; data unused)
    const int tn = (t + 1) & 15;
    kA = *reinterpret_cast<const uint4*>(kgbase + tn * 4096);
    kB = *reinterpret_cast<const uint4*>(kgbase + tn * 4096 + 8);
    vA = *reinterpret_cast<const uint4*>(vgbase + tn * 64);
    vB = *reinterpret_cast<const uint4*>(vgbase + tn * 64 + 8);

    // ---- S^T = K * Q^T  (two 32-row kpos subtiles) ----
    f32x16 s0 = {}, s1 = {};
#pragma unroll
    for (int ks = 0; ks < 4; ++ks) {
      const short8 a0 =
          *reinterpret_cast<const short8*>(lds + (raddr[ks] | po));
      const short8 a1 =
          *reinterpret_cast<const short8*>(lds + ((raddr[ks] + 4096) | po));
      s0 = __builtin_amdgcn_mfma_f32_32x32x16_bf16(a0, qf[ks], s0, 0, 0, 0);
      s1 = __builtin_amdgcn_mfma_f32_32x32x16_bf16(a1, qf[ks], s1, 0, 0, 0);
    }

    // ---- online softmax (base 2), deferred-max THR=8 ----
    float mv[8];
#pragma unroll
    for (int i = 0; i < 8; ++i)
      mv[i] = fmaxf(fmaxf(s0[i], s0[i + 8]), fmaxf(s1[i], s1[i + 8]));
#pragma unroll
    for (int i = 0; i < 4; ++i) mv[i] = fmaxf(mv[i], mv[i + 4]);
    float mx = fmaxf(fmaxf(mv[0], mv[1]), fmaxf(mv[2], mv[3]));
    mx = fmaxf(mx, __shfl_xor(mx, 32));

    const bool grow = mx > m_i + 8.0f;
    if (__any(grow)) {
      const float mn = grow ? mx : m_i;
      const float alpha = grow ? fexp2(m_i - mn) : 1.0f;
      l_i *= alpha;
#pragma unroll
      for (int i = 0; i < 16; ++i) { o[0][i] *= alpha; o[1][i] *= alpha; }
      m_i = mn;
    }

    float r0 = 0.f, r1 = 0.f, r2 = 0.f, r3 = 0.f;
#pragma unroll
    for (int i = 0; i < 16; i += 4) {
      s0[i + 0] = fexp2(s0[i + 0] - m_i); r0 += s0[i + 0];
      s0[i + 1] = fexp2(s0[i + 1] - m_i); r1 += s0[i + 1];
      s0[i + 2] = fexp2(s0[i + 2] - m_i); r2 += s0[i + 2];
      s0[i + 3] = fexp2(s0[i + 3] - m_i); r3 += s0[i + 3];
      s1[i + 0] = fexp2(s1[i + 0] - m_i); r0 += s1[i + 0];
      s1[i + 1] = fexp2(s1[i + 1] - m_i); r1 += s1[i + 1];
      s1[i + 2] = fexp2(s1[i + 2] - m_i); r2 += s1[i + 2];
      s1[i + 3] = fexp2(s1[i + 3] - m_i); r3 += s1[i + 3];
    }
    float rs = (r0 + r1) + (r2 + r3);
    rs += __shfl_xor(rs, 32);
    l_i += rs;

    // ---- P -> bf16 kpairs, redistribute across lane halves (in-register) ----
    short8 pf[4];
#pragma unroll
    for (int ks = 0; ks < 4; ++ks) {
      const int bb = 2 * (ks & 1);
      float p0, p1, p2, p3, p4, p5, p6, p7;
      if (ks < 2) {
        p0 = s0[4 * bb + 0]; p1 = s0[4 * bb + 1]; p2 = s0[4 * bb + 2];
        p3 = s0[4 * bb + 3]; p4 = s0[4 * bb + 4]; p5 = s0[4 * bb + 5];
        p6 = s0[4 * bb + 6]; p7 = s0[4 * bb + 7];
      } else {
        p0 = s1[4 * bb + 0]; p1 = s1[4 * bb + 1]; p2 = s1[4 * bb + 2];
        p3 = s1[4 * bb + 3]; p4 = s1[4 * bb + 4]; p5 = s1[4 * bb + 5];
        p6 = s1[4 * bb + 6]; p7 = s1[4 * bb + 7];
      }
      const uint32_t u00 = pk2(p0, p1), u01 = pk2(p2, p3);
      const uint32_t u10 = pk2(p4, p5), u11 = pk2(p6, p7);
      const uint2v se0 = __builtin_amdgcn_permlane32_swap(u00, u10, false, false);
      const uint2v se1 = __builtin_amdgcn_permlane32_swap(u01, u11, false, false);
      uint32_t fr[4] = {se0.x, se1.x, se0.y, se1.y};
      pf[ks] = *reinterpret_cast<short8*>(fr);
    }

    // ---- O^T += V^T * P^T ----
#pragma unroll
    for (int dt = 0; dt < 2; ++dt)
#pragma unroll
      for (int ks = 0; ks < 4; ++ks) {
        const short8 vf = *reinterpret_cast<const short8*>(
            lds + ((8192 + dt * 4096 + raddr[ks]) | po));
        o[dt] = __builtin_amdgcn_mfma_f32_32x32x16_bf16(vf, pf[ks], o[dt],
                                                        0, 0, 0);
      }
  }

  // ---- store partials ----
  if (lane < 32) ML[(size_t)combo * S_LEN + qrow] = float2{m_i, l_i};
  ushort* ob = Opart + (size_t)combo * 64 * S_LEN + qrow;
#pragma unroll
  for (int dt = 0; dt < 2; ++dt)
#pragma unroll
    for (int r = 0; r < 16; ++r) {
      const int d = 32 * dt + (r & 3) + 8 * (r >> 2) + 4 * hh;
      ob[(size_t)d * S_LEN] = bf1(o[dt][r]);
    }
}

// ---------------- combine the 4 kv-chunk partials ----------------
__global__ __launch_bounds__(256)
void combine(const ushort* __restrict__ Opart, const float2* __restrict__ ML,
             ushort* __restrict__ ob) {
  const int t = threadIdx.x;
  const int qq = t & 63, ds = t >> 6;
  const int q = blockIdx.x * 64 + qq;
  const int h = blockIdx.y;

  float m = -1e30f, mz[4], lz[4];
#pragma unroll
  for (int z = 0; z < 4; ++z) {
    const float2 v = ML[(size_t)(z * 8 + h) * S_LEN + q];
    mz[z] = v.x; lz[z] = v.y;
    m = fmaxf(m, v.x);
  }
  float wz[4], l = 0.f;
#pragma unroll
  for (int z = 0; z < 4; ++z) {
    wz[z] = fexp2(mz[z] - m);
    l += wz[z] * lz[z];
  }
  const float inv = 1.0f / l;

  float acc[16];
#pragma unroll
  for (int i = 0; i < 16; ++i) acc[i] = 0.f;
#pragma unroll
  for (int z = 0; z < 4; ++z) {
    const ushort* src =
        Opart + ((size_t)(z * 8 + h) * 64 + ds * 16) * S_LEN + q;
#pragma unroll
    for (int i = 0; i < 16; ++i)
      acc[i] += wz[z] * bf2f(src[(size_t)i * S_LEN]);
  }
  uint32_t pk[8];
#pragma unroll
  for (int i = 0; i < 8; ++i)
    pk[i] = pk2(acc[2 * i] * inv, acc[2 * i + 1] * inv);
  ushort* dst = ob + (size_t)q * DIM + h * 64 + ds * 16;
  *reinterpret_cast<uint4*>(dst) = *reinterpret_cast<uint4*>(pk);
  *reinterpret_cast<uint4*>(dst + 8) = *reinterpret_cast<uint4*>(pk + 4);
}

extern "C" void kernel_launch(void* const* d_in, const int* in_sizes, int n_in,
                              void* d_out, int out_size, void* d_ws, size_t ws_size,
                              hipStream_t stream) {
  const float* x  = (const float*)d_in[0];
  const float* qp = (const float*)d_in[1];
  const float* kp = (const float*)d_in[2];
  const float* vp = (const float*)d_in[3];
  const float* pp = (const float*)d_in[4];
  float* out = (float*)d_out;

  unsigned char* ws = (unsigned char*)d_ws;
  ushort* xb    = (ushort*)(ws);                       // 4 MB
  ushort* qkvb  = (ushort*)(ws + ((size_t)4 << 20));   // 12 MB [3][8] planes
  ushort* ob    = (ushort*)(ws + ((size_t)16 << 20));  // 4 MB [4096][512]
  ushort* wbT   = (ushort*)(ws + ((size_t)20 << 20));  // 1.5 MB
  ushort* ppT   = (ushort*)(ws + ((size_t)22 << 20));  // 0.5 MB
  ushort* opart = (ushort*)(ws + ((size_t)23 << 20));  // 16 MB [32][64][4096]
  float2* ml    = (float2*)(ws + ((size_t)39 << 20));  // 1 MB [32][4096]

  cast_x<<<dim3(1024), dim3(256), 0, stream>>>(x, xb);
  transpose_w<<<dim3(8, 8, 4), dim3(256), 0, stream>>>(qp, kp, vp, pp, wbT, ppT);
  gemm_bf16<0><<<dim3(32, 24), dim3(256), 0, stream>>>(xb, wbT, qkvb);
  attn_mfma32<<<dim3(32, 32), dim3(256), 0, stream>>>(qkvb, opart, ml);
  combine<<<dim3(64, 8), dim3(256), 0, stream>>>(opart, ml, ob);
  gemm_bf16<1><<<dim3(32, 8), dim3(256), 0, stream>>>(ob, ppT, out);
}